// Round 5
// baseline (1002.977 us; speedup 1.0000x reference)
//
#include <hip/hip_runtime.h>
#include <hip/hip_bf16.h>

#define NF 64        // node/edge feature dim
#define N_OUT 128    // output dim
#define CAT 192      // concat dim = 3*64

// DIAGNOSTIC ROUND: h1_kernel repeats its work 6x, est_kernel 4x, so each
// single dispatch exceeds the ~330us harness-fill cutoff and appears in the
// rocprof top-5 with counters. Work is idempotent -> output unchanged.
#define H1_REP 6
#define EST_REP 4

typedef __attribute__((ext_vector_type(4))) float f32x4;
typedef __attribute__((ext_vector_type(8))) short bf16x8;

__device__ inline short f2bf(float x) {   // round-to-nearest-even bf16
  unsigned u = __float_as_uint(x);
  unsigned r = (u + 0x7fff + ((u >> 16) & 1)) >> 16;
  return (short)r;
}

__device__ inline f32x4 sx4(f32x4 v, int m) {
  f32x4 r;
  r.x = __shfl_xor(v.x, m, 64);
  r.y = __shfl_xor(v.y, m, 64);
  r.z = __shfl_xor(v.z, m, 64);
  r.w = __shfl_xor(v.w, m, 64);
  return r;
}

// ---------------- degree histogram ----------------
__global__ __launch_bounds__(256) void deg_kernel(const int* __restrict__ dst,
                                                  int* __restrict__ deg, int n_edges) {
  int i = blockIdx.x * blockDim.x + threadIdx.x;
  int stride = gridDim.x * blockDim.x;
  for (; i < n_edges; i += stride) {
    int d = __builtin_nontemporal_load(&dst[i]);
    atomicAdd(&deg[d], 1);
  }
}

// ---------------- parallel scan ----------------
__global__ __launch_bounds__(256) void scanA_kernel(const int* __restrict__ deg,
                                                    int* __restrict__ offs,
                                                    float* __restrict__ norm,
                                                    int* __restrict__ bsum, int n) {
  int tid = threadIdx.x;
  int i = blockIdx.x * 256 + tid;
  int lane = tid & 63, wid = tid >> 6;
  int v = (i < n) ? deg[i] : 0;
  int s = v;
  #pragma unroll
  for (int o = 1; o < 64; o <<= 1) {
    int t = __shfl_up(s, o, 64);
    if (lane >= o) s += t;
  }
  __shared__ int ws[4], wb[4];
  if (lane == 63) ws[wid] = s;
  __syncthreads();
  if (tid == 0) {
    int run = 0;
    #pragma unroll
    for (int w = 0; w < 4; ++w) { wb[w] = run; run += ws[w]; }
    bsum[blockIdx.x] = run;
  }
  __syncthreads();
  if (i < n) {
    offs[i] = wb[wid] + s - v;
    norm[i] = rsqrtf(fmaxf((float)v, 1.0f));
  }
}

__global__ __launch_bounds__(256) void scanB_kernel(int* __restrict__ bsum, int nb) {
  int tid = threadIdx.x, lane = tid & 63, wid = tid >> 6;
  int v = (tid < nb) ? bsum[tid] : 0;
  int s = v;
  #pragma unroll
  for (int o = 1; o < 64; o <<= 1) {
    int t = __shfl_up(s, o, 64);
    if (lane >= o) s += t;
  }
  __shared__ int ws[4], wb[4];
  if (lane == 63) ws[wid] = s;
  __syncthreads();
  if (tid == 0) {
    int run = 0;
    #pragma unroll
    for (int w = 0; w < 4; ++w) { wb[w] = run; run += ws[w]; }
  }
  __syncthreads();
  if (tid < nb) bsum[tid] = wb[wid] + s - v;
}

__global__ __launch_bounds__(256) void scanC_kernel(int* __restrict__ offs,
                                                    const int* __restrict__ bsum, int n) {
  int i = blockIdx.x * 256 + threadIdx.x;
  if (i < n) offs[i] += bsum[blockIdx.x];
}

// ---------------- CSR bucket fill: offs doubles as cursor ----------------
__global__ __launch_bounds__(256) void fill_kernel(const int* __restrict__ src,
                                                   const int* __restrict__ dst,
                                                   int* __restrict__ offs,
                                                   int2* __restrict__ csr, int n_edges) {
  int i = blockIdx.x * blockDim.x + threadIdx.x;
  int stride = gridDim.x * blockDim.x;
  for (; i < n_edges; i += stride) {
    int d = __builtin_nontemporal_load(&dst[i]);
    int s = __builtin_nontemporal_load(&src[i]);
    int p = atomicAdd(&offs[d], 1);
    csr[p] = make_int2(i, s);
  }
}

// ---------------- hop 1 (repeated H1_REP x for diagnosis) ----------------
__global__ __launch_bounds__(256) void h1_kernel(const float* __restrict__ edge_feat,
                                                 const int2* __restrict__ csr,
                                                 const int* __restrict__ offs,
                                                 float* __restrict__ h1, int n_nodes) {
  int n = blockIdx.x * 4 + (threadIdx.x >> 6);
  if (n >= n_nodes) return;
  int l = threadIdx.x & 63;
  int l15 = l & 15, l4 = l >> 4;
  int kb = n ? offs[n - 1] : 0;
  int ke = offs[n];
  #pragma unroll 1
  for (int rep = 0; rep < H1_REP; ++rep) {
    f32x4 acc0 = {0.f, 0.f, 0.f, 0.f}, acc1 = {0.f, 0.f, 0.f, 0.f};
    int k = kb;
    for (; k + 8 <= ke; k += 8) {
      int e0 = csr[k + l4].x;
      int e1 = csr[k + 4 + l4].x;
      f32x4 v0 = __builtin_nontemporal_load((const f32x4*)&edge_feat[(size_t)e0 * NF + l15 * 4]);
      f32x4 v1 = __builtin_nontemporal_load((const f32x4*)&edge_feat[(size_t)e1 * NF + l15 * 4]);
      acc0 += v0;
      acc1 += v1;
    }
    if (k + 4 <= ke) {
      int e = csr[k + l4].x;
      acc0 += __builtin_nontemporal_load((const f32x4*)&edge_feat[(size_t)e * NF + l15 * 4]);
      k += 4;
    }
    int rem = ke - k;   // 0..3
    if (l4 < rem) {
      int e = csr[k + l4].x;
      acc1 += __builtin_nontemporal_load((const f32x4*)&edge_feat[(size_t)e * NF + l15 * 4]);
    }
    f32x4 t = acc0 + acc1;
    t += sx4(t, 16);
    t += sx4(t, 32);
    if (l4 == 0) *(f32x4*)&h1[(size_t)n * NF + l15 * 4] = t;
  }
}

// ---------------- hop 2 ----------------
__global__ __launch_bounds__(256) void h2_kernel(const float* __restrict__ h1,
                                                 const int2* __restrict__ csr,
                                                 const int* __restrict__ offs,
                                                 float* __restrict__ h2, int n_nodes) {
  int n = blockIdx.x * 4 + (threadIdx.x >> 6);
  if (n >= n_nodes) return;
  int l = threadIdx.x & 63;
  int l15 = l & 15, l4 = l >> 4;
  int kb = n ? offs[n - 1] : 0;
  int ke = offs[n];
  f32x4 acc0 = {0.f, 0.f, 0.f, 0.f}, acc1 = {0.f, 0.f, 0.f, 0.f};
  int k = kb;
  for (; k + 8 <= ke; k += 8) {
    int s0 = csr[k + l4].y;
    int s1 = csr[k + 4 + l4].y;
    acc0 += *(const f32x4*)&h1[(size_t)s0 * NF + l15 * 4];
    acc1 += *(const f32x4*)&h1[(size_t)s1 * NF + l15 * 4];
  }
  if (k + 4 <= ke) {
    int s = csr[k + l4].y;
    acc0 += *(const f32x4*)&h1[(size_t)s * NF + l15 * 4];
    k += 4;
  }
  int rem = ke - k;
  if (l4 < rem) {
    int s = csr[k + l4].y;
    acc1 += *(const f32x4*)&h1[(size_t)s * NF + l15 * 4];
  }
  f32x4 t = acc0 + acc1;
  t += sx4(t, 16);
  t += sx4(t, 32);
  if (l4 == 0) *(f32x4*)&h2[(size_t)n * NF + l15 * 4] = t;
}

// ---------------- GEMM via bf16 MFMA ----------------
__global__ __launch_bounds__(256) void gemm_kernel(const float* __restrict__ node_feat,
                                                   const float* __restrict__ h1,
                                                   const float* __restrict__ h2,
                                                   const float* __restrict__ norm,
                                                   const float* __restrict__ W,
                                                   const float* __restrict__ bias,
                                                   float* __restrict__ rst, int n_nodes) {
  __shared__ short F[32 * 200];
  int tid = threadIdx.x;
  int l = tid & 63, w = tid >> 6;
  int l15 = l & 15, l4 = l >> 4;

  bf16x8 Bf[6][2];
  #pragma unroll
  for (int c = 0; c < 2; ++c) {
    int col = w * 32 + c * 16 + l15;
    const float* wp = &W[(size_t)col * CAT];
    #pragma unroll
    for (int ks = 0; ks < 6; ++ks) {
      int k0 = ks * 32 + l4 * 8;
      bf16x8 b;
      #pragma unroll
      for (int j = 0; j < 8; ++j) b[j] = f2bf(wp[k0 + j]);
      Bf[ks][c] = b;
    }
  }
  float bias0 = bias[w * 32 + l15];
  float bias1 = bias[w * 32 + 16 + l15];

  int tiles = (n_nodes + 31) / 32;
  for (int tile = blockIdx.x; tile < tiles; tile += gridDim.x) {
    int nbase = tile * 32;
    __syncthreads();
    for (int idx = tid; idx < 768; idx += 256) {
      int m = idx / 24, q = idx - m * 24;
      int n = nbase + m;
      bf16x8 pk;
      if (n < n_nodes) {
        const float* sp;
        float scale = 1.f;
        if (q < 8)       sp = &node_feat[(size_t)n * NF + q * 8];
        else if (q < 16) { sp = &h1[(size_t)n * NF + (q - 8) * 8]; scale = norm[n]; }
        else             { sp = &h2[(size_t)n * NF + (q - 16) * 8]; scale = norm[n]; }
        f32x4 v0 = *(const f32x4*)sp;
        f32x4 v1 = *(const f32x4*)(sp + 4);
        pk[0] = f2bf(v0.x * scale); pk[1] = f2bf(v0.y * scale);
        pk[2] = f2bf(v0.z * scale); pk[3] = f2bf(v0.w * scale);
        pk[4] = f2bf(v1.x * scale); pk[5] = f2bf(v1.y * scale);
        pk[6] = f2bf(v1.z * scale); pk[7] = f2bf(v1.w * scale);
      } else {
        pk = bf16x8{0,0,0,0,0,0,0,0};
      }
      *(bf16x8*)&F[m * 200 + q * 8] = pk;
    }
    __syncthreads();
    f32x4 acc00 = {0.f,0.f,0.f,0.f}, acc01 = {0.f,0.f,0.f,0.f};
    f32x4 acc10 = {0.f,0.f,0.f,0.f}, acc11 = {0.f,0.f,0.f,0.f};
    #pragma unroll
    for (int ks = 0; ks < 6; ++ks) {
      bf16x8 a0 = *(const bf16x8*)&F[l15 * 200 + ks * 32 + l4 * 8];
      bf16x8 a1 = *(const bf16x8*)&F[(16 + l15) * 200 + ks * 32 + l4 * 8];
      acc00 = __builtin_amdgcn_mfma_f32_16x16x32_bf16(a0, Bf[ks][0], acc00, 0, 0, 0);
      acc01 = __builtin_amdgcn_mfma_f32_16x16x32_bf16(a0, Bf[ks][1], acc01, 0, 0, 0);
      acc10 = __builtin_amdgcn_mfma_f32_16x16x32_bf16(a1, Bf[ks][0], acc10, 0, 0, 0);
      acc11 = __builtin_amdgcn_mfma_f32_16x16x32_bf16(a1, Bf[ks][1], acc11, 0, 0, 0);
    }
    #pragma unroll
    for (int rt = 0; rt < 2; ++rt) {
      f32x4 ac0 = rt ? acc10 : acc00;
      f32x4 ac1 = rt ? acc11 : acc01;
      #pragma unroll
      for (int r = 0; r < 4; ++r) {
        int n = nbase + rt * 16 + l4 * 4 + r;
        if (n < n_nodes) {
          int o0 = w * 32 + l15;
          rst[(size_t)n * N_OUT + o0] = ac0[r] + bias0;
          rst[(size_t)n * N_OUT + o0 + 16] = ac1[r] + bias1;
        }
      }
    }
  }
}

// ---------------- est = rst[src] (repeated EST_REP x for diagnosis) ----------------
__global__ __launch_bounds__(256) void est_kernel(const float* __restrict__ rst,
                                                  const int* __restrict__ src,
                                                  float* __restrict__ est, int n_edges) {
  const f32x4* r4 = (const f32x4*)rst;
  f32x4* e4 = (f32x4*)est;
  int total = n_edges * 32;
  int stride = gridDim.x * blockDim.x;
  #pragma unroll 1
  for (int rep = 0; rep < EST_REP; ++rep) {
    int i = blockIdx.x * blockDim.x + threadIdx.x;
    for (; i < total; i += stride) {
      int e = i >> 5, c = i & 31;
      f32x4 v = r4[(size_t)src[e] * 32 + c];
      __builtin_nontemporal_store(v, &e4[i]);
    }
  }
}

extern "C" void kernel_launch(void* const* d_in, const int* in_sizes, int n_in,
                              void* d_out, int out_size, void* d_ws, size_t ws_size,
                              hipStream_t stream) {
  const float* node_feat = (const float*)d_in[0];
  const float* edge_feat = (const float*)d_in[1];
  const float* W = (const float*)d_in[2];
  const float* bias = (const float*)d_in[3];
  const int* src = (const int*)d_in[4];
  const int* dst = (const int*)d_in[5];
  int n_nodes = in_sizes[0] / NF;
  int n_edges = in_sizes[4];

  size_t off = 0;
  auto take = [&](size_t bytes) -> void* {
    void* p = (char*)d_ws + off;
    off += (bytes + 255) & ~(size_t)255;
    return p;
  };
  int* deg = (int*)take((size_t)n_nodes * 4);
  int* offs = (int*)take(((size_t)n_nodes + 1) * 4);
  float* norm = (float*)take((size_t)n_nodes * 4);
  int* bsum = (int*)take(256 * 4);
  int2* csr = (int2*)take((size_t)n_edges * 8);
  float* h1 = (float*)take((size_t)n_nodes * NF * 4);
  float* h2 = (float*)take((size_t)n_nodes * NF * 4);

  float* rst = (float*)d_out;
  float* est = rst + (size_t)n_nodes * N_OUT;

  hipMemsetAsync(deg, 0, (size_t)n_nodes * 4, stream);

  deg_kernel<<<2048, 256, 0, stream>>>(dst, deg, n_edges);
  int nbs = (n_nodes + 255) / 256;
  scanA_kernel<<<nbs, 256, 0, stream>>>(deg, offs, norm, bsum, n_nodes);
  scanB_kernel<<<1, 256, 0, stream>>>(bsum, nbs);
  scanC_kernel<<<nbs, 256, 0, stream>>>(offs, bsum, n_nodes);
  fill_kernel<<<2048, 256, 0, stream>>>(src, dst, offs, csr, n_edges);
  int nb = (n_nodes + 3) / 4;
  h1_kernel<<<nb, 256, 0, stream>>>(edge_feat, csr, offs, h1, n_nodes);
  h2_kernel<<<nb, 256, 0, stream>>>(h1, csr, offs, h2, n_nodes);
  gemm_kernel<<<512, 256, 0, stream>>>(node_feat, h1, h2, norm, W, bias, rst, n_nodes);
  est_kernel<<<4096, 256, 0, stream>>>(rst, src, est, n_edges);
}

// Round 6
// 475.894 us; speedup vs baseline: 2.1076x; 2.1076x over previous
//
#include <hip/hip_runtime.h>
#include <hip/hip_bf16.h>

#define NF 64        // node/edge feature dim
#define N_OUT 128    // output dim
#define CAT 192      // concat dim = 3*64

typedef __attribute__((ext_vector_type(4))) float f32x4;
typedef __attribute__((ext_vector_type(8))) short bf16x8;

__device__ inline short f2bf(float x) {   // round-to-nearest-even bf16
  unsigned u = __float_as_uint(x);
  unsigned r = (u + 0x7fff + ((u >> 16) & 1)) >> 16;
  return (short)r;
}

__device__ inline f32x4 sx4(f32x4 v, int m) {
  f32x4 r;
  r.x = __shfl_xor(v.x, m, 64);
  r.y = __shfl_xor(v.y, m, 64);
  r.z = __shfl_xor(v.z, m, 64);
  r.w = __shfl_xor(v.w, m, 64);
  return r;
}

// ---------------- dual degree histogram (in by dst, out by src) ----------------
__global__ __launch_bounds__(256) void deg_kernel(const int* __restrict__ dst,
                                                  const int* __restrict__ src,
                                                  int* __restrict__ deg_in,
                                                  int* __restrict__ deg_out, int n_edges) {
  int i = blockIdx.x * blockDim.x + threadIdx.x;
  int stride = gridDim.x * blockDim.x;
  for (; i < n_edges; i += stride) {
    atomicAdd(&deg_in[dst[i]], 1);
    atomicAdd(&deg_out[src[i]], 1);
  }
}

// ---------------- parallel scan (per-array; norm optional) ----------------
__global__ __launch_bounds__(256) void scanA_kernel(const int* __restrict__ deg,
                                                    int* __restrict__ offs,
                                                    float* __restrict__ norm,
                                                    int* __restrict__ bsum, int n) {
  int tid = threadIdx.x;
  int i = blockIdx.x * 256 + tid;
  int lane = tid & 63, wid = tid >> 6;
  int v = (i < n) ? deg[i] : 0;
  int s = v;
  #pragma unroll
  for (int o = 1; o < 64; o <<= 1) {
    int t = __shfl_up(s, o, 64);
    if (lane >= o) s += t;
  }
  __shared__ int ws[4], wb[4];
  if (lane == 63) ws[wid] = s;
  __syncthreads();
  if (tid == 0) {
    int run = 0;
    #pragma unroll
    for (int w = 0; w < 4; ++w) { wb[w] = run; run += ws[w]; }
    bsum[blockIdx.x] = run;
  }
  __syncthreads();
  if (i < n) {
    offs[i] = wb[wid] + s - v;
    if (norm) norm[i] = rsqrtf(fmaxf((float)v, 1.0f));
  }
}

// block 0 scans bsum_in, block 1 scans bsum_out (each <= 256 entries)
__global__ __launch_bounds__(256) void scanB_kernel(int* __restrict__ bsum_in,
                                                    int* __restrict__ bsum_out, int nb) {
  int* bsum = blockIdx.x ? bsum_out : bsum_in;
  int tid = threadIdx.x, lane = tid & 63, wid = tid >> 6;
  int v = (tid < nb) ? bsum[tid] : 0;
  int s = v;
  #pragma unroll
  for (int o = 1; o < 64; o <<= 1) {
    int t = __shfl_up(s, o, 64);
    if (lane >= o) s += t;
  }
  __shared__ int ws[4], wb[4];
  if (lane == 63) ws[wid] = s;
  __syncthreads();
  if (tid == 0) {
    int run = 0;
    #pragma unroll
    for (int w = 0; w < 4; ++w) { wb[w] = run; run += ws[w]; }
  }
  __syncthreads();
  if (tid < nb) bsum[tid] = wb[wid] + s - v;
}

// blocks [0,nbs) add bases to offs_in; [nbs,2nbs) to offs_out
__global__ __launch_bounds__(256) void scanC_kernel(int* __restrict__ offs_in,
                                                    const int* __restrict__ bsum_in,
                                                    int* __restrict__ offs_out,
                                                    const int* __restrict__ bsum_out,
                                                    int n, int nbs) {
  int b = blockIdx.x;
  int* offs = (b < nbs) ? offs_in : offs_out;
  const int* bsum = (b < nbs) ? bsum_in : bsum_out;
  int bb = (b < nbs) ? b : b - nbs;
  int i = bb * 256 + threadIdx.x;
  if (i < n) offs[i] += bsum[bb];
}

// ---------------- dual CSR fill; offs arrays double as cursors ----------------
// Afterwards offs_*[x] = end of bucket x; bucket x spans [x? offs[x-1]:0, offs[x]).
__global__ __launch_bounds__(256) void fill_kernel(const int* __restrict__ src,
                                                   const int* __restrict__ dst,
                                                   int* __restrict__ offs_in,
                                                   int* __restrict__ offs_out,
                                                   int2* __restrict__ csr_in,
                                                   int* __restrict__ csr_out, int n_edges) {
  int i = blockIdx.x * blockDim.x + threadIdx.x;
  int stride = gridDim.x * blockDim.x;
  for (; i < n_edges; i += stride) {
    int d = dst[i];
    int s = src[i];
    int p = atomicAdd(&offs_in[d], 1);
    csr_in[p] = make_int2(i, s);
    int q = atomicAdd(&offs_out[s], 1);
    csr_out[q] = i;
  }
}

// ---------------- hop 1: 16 lanes x float4 per row, 4 rows per wave-load ----------------
__global__ __launch_bounds__(256) void h1_kernel(const float* __restrict__ edge_feat,
                                                 const int2* __restrict__ csr,
                                                 const int* __restrict__ offs,
                                                 float* __restrict__ h1, int n_nodes) {
  int n = blockIdx.x * 4 + (threadIdx.x >> 6);
  if (n >= n_nodes) return;
  int l = threadIdx.x & 63;
  int l15 = l & 15, l4 = l >> 4;
  int kb = n ? offs[n - 1] : 0;
  int ke = offs[n];
  f32x4 acc0 = {0.f, 0.f, 0.f, 0.f}, acc1 = {0.f, 0.f, 0.f, 0.f};
  int k = kb;
  for (; k + 8 <= ke; k += 8) {
    int e0 = csr[k + l4].x;
    int e1 = csr[k + 4 + l4].x;
    f32x4 v0 = __builtin_nontemporal_load((const f32x4*)&edge_feat[(size_t)e0 * NF + l15 * 4]);
    f32x4 v1 = __builtin_nontemporal_load((const f32x4*)&edge_feat[(size_t)e1 * NF + l15 * 4]);
    acc0 += v0;
    acc1 += v1;
  }
  if (k + 4 <= ke) {
    int e = csr[k + l4].x;
    acc0 += __builtin_nontemporal_load((const f32x4*)&edge_feat[(size_t)e * NF + l15 * 4]);
    k += 4;
  }
  int rem = ke - k;   // 0..3
  if (l4 < rem) {
    int e = csr[k + l4].x;
    acc1 += __builtin_nontemporal_load((const f32x4*)&edge_feat[(size_t)e * NF + l15 * 4]);
  }
  f32x4 t = acc0 + acc1;
  t += sx4(t, 16);
  t += sx4(t, 32);
  if (l4 == 0) *(f32x4*)&h1[(size_t)n * NF + l15 * 4] = t;
}

// ---------------- hop 2: same structure, rows from h1 (cached) ----------------
__global__ __launch_bounds__(256) void h2_kernel(const float* __restrict__ h1,
                                                 const int2* __restrict__ csr,
                                                 const int* __restrict__ offs,
                                                 float* __restrict__ h2, int n_nodes) {
  int n = blockIdx.x * 4 + (threadIdx.x >> 6);
  if (n >= n_nodes) return;
  int l = threadIdx.x & 63;
  int l15 = l & 15, l4 = l >> 4;
  int kb = n ? offs[n - 1] : 0;
  int ke = offs[n];
  f32x4 acc0 = {0.f, 0.f, 0.f, 0.f}, acc1 = {0.f, 0.f, 0.f, 0.f};
  int k = kb;
  for (; k + 8 <= ke; k += 8) {
    int s0 = csr[k + l4].y;
    int s1 = csr[k + 4 + l4].y;
    acc0 += *(const f32x4*)&h1[(size_t)s0 * NF + l15 * 4];
    acc1 += *(const f32x4*)&h1[(size_t)s1 * NF + l15 * 4];
  }
  if (k + 4 <= ke) {
    int s = csr[k + l4].y;
    acc0 += *(const f32x4*)&h1[(size_t)s * NF + l15 * 4];
    k += 4;
  }
  int rem = ke - k;
  if (l4 < rem) {
    int s = csr[k + l4].y;
    acc1 += *(const f32x4*)&h1[(size_t)s * NF + l15 * 4];
  }
  f32x4 t = acc0 + acc1;
  t += sx4(t, 16);
  t += sx4(t, 32);
  if (l4 == 0) *(f32x4*)&h2[(size_t)n * NF + l15 * 4] = t;
}

// ---------------- fused GEMM + est scatter ----------------
// rst tile (32x128) computed via bf16 MFMA, staged to LDS, then written to rst
// (sequential) and to est[e] for every out-edge e of the tile's nodes (scattered,
// NT). Eliminates the separate est kernel and its amplified rst re-read.
__global__ __launch_bounds__(256) void gemm_kernel(const float* __restrict__ node_feat,
                                                   const float* __restrict__ h1,
                                                   const float* __restrict__ h2,
                                                   const float* __restrict__ norm,
                                                   const float* __restrict__ W,
                                                   const float* __restrict__ bias,
                                                   const int* __restrict__ offs_out,
                                                   const int* __restrict__ csr_out,
                                                   float* __restrict__ rst,
                                                   float* __restrict__ est, int n_nodes) {
  __shared__ short F[32 * 200];       // 12800 B bf16 A-tile
  __shared__ float R[32][132];        // 16896 B rst tile (pad +4 breaks bank alias)
  int tid = threadIdx.x;
  int l = tid & 63, w = tid >> 6;
  int l15 = l & 15, l4 = l >> 4;

  bf16x8 Bf[6][2];
  #pragma unroll
  for (int c = 0; c < 2; ++c) {
    int col = w * 32 + c * 16 + l15;
    const float* wp = &W[(size_t)col * CAT];
    #pragma unroll
    for (int ks = 0; ks < 6; ++ks) {
      int k0 = ks * 32 + l4 * 8;
      bf16x8 b;
      #pragma unroll
      for (int j = 0; j < 8; ++j) b[j] = f2bf(wp[k0 + j]);
      Bf[ks][c] = b;
    }
  }
  float bias0 = bias[w * 32 + l15];
  float bias1 = bias[w * 32 + 16 + l15];

  int cc = tid & 31, g = tid >> 5;    // est-writer decomposition: 8 groups x 32 lanes
  f32x4* e4 = (f32x4*)est;

  int tiles = (n_nodes + 31) / 32;
  for (int tile = blockIdx.x; tile < tiles; tile += gridDim.x) {
    int nbase = tile * 32;
    __syncthreads();   // previous iteration's readers done with F and R
    for (int idx = tid; idx < 768; idx += 256) {
      int m = idx / 24, q = idx - m * 24;
      int n = nbase + m;
      bf16x8 pk;
      if (n < n_nodes) {
        const float* sp;
        float scale = 1.f;
        if (q < 8)       sp = &node_feat[(size_t)n * NF + q * 8];
        else if (q < 16) { sp = &h1[(size_t)n * NF + (q - 8) * 8]; scale = norm[n]; }
        else             { sp = &h2[(size_t)n * NF + (q - 16) * 8]; scale = norm[n]; }
        f32x4 v0 = *(const f32x4*)sp;
        f32x4 v1 = *(const f32x4*)(sp + 4);
        pk[0] = f2bf(v0.x * scale); pk[1] = f2bf(v0.y * scale);
        pk[2] = f2bf(v0.z * scale); pk[3] = f2bf(v0.w * scale);
        pk[4] = f2bf(v1.x * scale); pk[5] = f2bf(v1.y * scale);
        pk[6] = f2bf(v1.z * scale); pk[7] = f2bf(v1.w * scale);
      } else {
        pk = bf16x8{0,0,0,0,0,0,0,0};
      }
      *(bf16x8*)&F[m * 200 + q * 8] = pk;
    }
    __syncthreads();
    f32x4 acc00 = {0.f,0.f,0.f,0.f}, acc01 = {0.f,0.f,0.f,0.f};
    f32x4 acc10 = {0.f,0.f,0.f,0.f}, acc11 = {0.f,0.f,0.f,0.f};
    #pragma unroll
    for (int ks = 0; ks < 6; ++ks) {
      bf16x8 a0 = *(const bf16x8*)&F[l15 * 200 + ks * 32 + l4 * 8];
      bf16x8 a1 = *(const bf16x8*)&F[(16 + l15) * 200 + ks * 32 + l4 * 8];
      acc00 = __builtin_amdgcn_mfma_f32_16x16x32_bf16(a0, Bf[ks][0], acc00, 0, 0, 0);
      acc01 = __builtin_amdgcn_mfma_f32_16x16x32_bf16(a0, Bf[ks][1], acc01, 0, 0, 0);
      acc10 = __builtin_amdgcn_mfma_f32_16x16x32_bf16(a1, Bf[ks][0], acc10, 0, 0, 0);
      acc11 = __builtin_amdgcn_mfma_f32_16x16x32_bf16(a1, Bf[ks][1], acc11, 0, 0, 0);
    }
    // stage tile to LDS: D[row=rt*16+l4*4+r][col=w*32+(c?16:0)+l15]
    #pragma unroll
    for (int rt = 0; rt < 2; ++rt) {
      f32x4 ac0 = rt ? acc10 : acc00;
      f32x4 ac1 = rt ? acc11 : acc01;
      #pragma unroll
      for (int r = 0; r < 4; ++r) {
        int row = rt * 16 + l4 * 4 + r;
        R[row][w * 32 + l15] = ac0[r] + bias0;
        R[row][w * 32 + 16 + l15] = ac1[r] + bias1;
      }
    }
    __syncthreads();
    // rst write: coalesced float4, 8 rows per pass
    for (int idx = tid; idx < 32 * 32; idx += 256) {
      int m = idx >> 5, c = idx & 31;
      int n = nbase + m;
      if (n < n_nodes)
        *(f32x4*)&rst[(size_t)n * N_OUT + c * 4] = *(const f32x4*)&R[m][c * 4];
    }
    // est scatter: group g takes every 8th out-edge of node m; 32 lanes cover the row
    for (int m = 0; m < 32; ++m) {
      int n = nbase + m;
      if (n >= n_nodes) break;
      int b = n ? offs_out[n - 1] : 0;
      int eend = offs_out[n];
      if (b == eend) continue;
      f32x4 v = *(const f32x4*)&R[m][cc * 4];
      for (int j = b + g; j < eend; j += 8) {
        int e = csr_out[j];
        __builtin_nontemporal_store(v, &e4[(size_t)e * 32 + cc]);
      }
    }
  }
}

extern "C" void kernel_launch(void* const* d_in, const int* in_sizes, int n_in,
                              void* d_out, int out_size, void* d_ws, size_t ws_size,
                              hipStream_t stream) {
  const float* node_feat = (const float*)d_in[0];
  const float* edge_feat = (const float*)d_in[1];
  const float* W = (const float*)d_in[2];
  const float* bias = (const float*)d_in[3];
  const int* src = (const int*)d_in[4];
  const int* dst = (const int*)d_in[5];
  int n_nodes = in_sizes[0] / NF;
  int n_edges = in_sizes[4];

  size_t off = 0;
  auto take = [&](size_t bytes) -> void* {
    void* p = (char*)d_ws + off;
    off += (bytes + 255) & ~(size_t)255;
    return p;
  };
  int* deg2 = (int*)take((size_t)n_nodes * 8);        // deg_in | deg_out, one memset
  int* deg_in = deg2;
  int* deg_out = deg2 + n_nodes;
  int* offs_in = (int*)take((size_t)n_nodes * 4);
  int* offs_out = (int*)take((size_t)n_nodes * 4);
  float* norm = (float*)take((size_t)n_nodes * 4);
  int* bsum_in = (int*)take(256 * 4);
  int* bsum_out = (int*)take(256 * 4);
  int2* csr_in = (int2*)take((size_t)n_edges * 8);
  int* csr_out = (int*)take((size_t)n_edges * 4);
  float* h1 = (float*)take((size_t)n_nodes * NF * 4);
  float* h2 = (float*)take((size_t)n_nodes * NF * 4);

  float* rst = (float*)d_out;
  float* est = rst + (size_t)n_nodes * N_OUT;

  hipMemsetAsync(deg2, 0, (size_t)n_nodes * 8, stream);

  deg_kernel<<<2048, 256, 0, stream>>>(dst, src, deg_in, deg_out, n_edges);
  int nbs = (n_nodes + 255) / 256;     // 196 <= 256
  scanA_kernel<<<nbs, 256, 0, stream>>>(deg_in, offs_in, norm, bsum_in, n_nodes);
  scanA_kernel<<<nbs, 256, 0, stream>>>(deg_out, offs_out, nullptr, bsum_out, n_nodes);
  scanB_kernel<<<2, 256, 0, stream>>>(bsum_in, bsum_out, nbs);
  scanC_kernel<<<2 * nbs, 256, 0, stream>>>(offs_in, bsum_in, offs_out, bsum_out,
                                            n_nodes, nbs);
  fill_kernel<<<2048, 256, 0, stream>>>(src, dst, offs_in, offs_out,
                                        csr_in, csr_out, n_edges);
  int nb = (n_nodes + 3) / 4;
  h1_kernel<<<nb, 256, 0, stream>>>(edge_feat, csr_in, offs_in, h1, n_nodes);
  h2_kernel<<<nb, 256, 0, stream>>>(h1, csr_in, offs_in, h2, n_nodes);
  gemm_kernel<<<512, 256, 0, stream>>>(node_feat, h1, h2, norm, W, bias,
                                       offs_out, csr_out, rst, est, n_nodes);
}

// Round 7
// 389.224 us; speedup vs baseline: 2.5769x; 1.2227x over previous
//
#include <hip/hip_runtime.h>
#include <hip/hip_bf16.h>

#define NF 64        // node/edge feature dim
#define N_OUT 128    // output dim
#define CAT 192      // concat dim = 3*64

typedef __attribute__((ext_vector_type(4))) float f32x4;
typedef __attribute__((ext_vector_type(8))) short bf16x8;

__device__ inline short f2bf(float x) {   // round-to-nearest-even bf16
  unsigned u = __float_as_uint(x);
  unsigned r = (u + 0x7fff + ((u >> 16) & 1)) >> 16;
  return (short)r;
}

__device__ inline f32x4 sx4(f32x4 v, int m) {
  f32x4 r;
  r.x = __shfl_xor(v.x, m, 64);
  r.y = __shfl_xor(v.y, m, 64);
  r.z = __shfl_xor(v.z, m, 64);
  r.w = __shfl_xor(v.w, m, 64);
  return r;
}

// ---------------- degree histogram ----------------
__global__ __launch_bounds__(256) void deg_kernel(const int* __restrict__ dst,
                                                  int* __restrict__ deg, int n_edges) {
  int i = blockIdx.x * blockDim.x + threadIdx.x;
  int stride = gridDim.x * blockDim.x;
  for (; i < n_edges; i += stride) {
    int d = __builtin_nontemporal_load(&dst[i]);
    atomicAdd(&deg[d], 1);
  }
}

// ---------------- parallel scan ----------------
__global__ __launch_bounds__(256) void scanA_kernel(const int* __restrict__ deg,
                                                    int* __restrict__ offs,
                                                    float* __restrict__ norm,
                                                    int* __restrict__ bsum, int n) {
  int tid = threadIdx.x;
  int i = blockIdx.x * 256 + tid;
  int lane = tid & 63, wid = tid >> 6;
  int v = (i < n) ? deg[i] : 0;
  int s = v;
  #pragma unroll
  for (int o = 1; o < 64; o <<= 1) {
    int t = __shfl_up(s, o, 64);
    if (lane >= o) s += t;
  }
  __shared__ int ws[4], wb[4];
  if (lane == 63) ws[wid] = s;
  __syncthreads();
  if (tid == 0) {
    int run = 0;
    #pragma unroll
    for (int w = 0; w < 4; ++w) { wb[w] = run; run += ws[w]; }
    bsum[blockIdx.x] = run;
  }
  __syncthreads();
  if (i < n) {
    offs[i] = wb[wid] + s - v;
    norm[i] = rsqrtf(fmaxf((float)v, 1.0f));
  }
}

__global__ __launch_bounds__(256) void scanB_kernel(int* __restrict__ bsum, int nb) {
  int tid = threadIdx.x, lane = tid & 63, wid = tid >> 6;
  int v = (tid < nb) ? bsum[tid] : 0;
  int s = v;
  #pragma unroll
  for (int o = 1; o < 64; o <<= 1) {
    int t = __shfl_up(s, o, 64);
    if (lane >= o) s += t;
  }
  __shared__ int ws[4], wb[4];
  if (lane == 63) ws[wid] = s;
  __syncthreads();
  if (tid == 0) {
    int run = 0;
    #pragma unroll
    for (int w = 0; w < 4; ++w) { wb[w] = run; run += ws[w]; }
  }
  __syncthreads();
  if (tid < nb) bsum[tid] = wb[wid] + s - v;
}

__global__ __launch_bounds__(256) void scanC_kernel(int* __restrict__ offs,
                                                    const int* __restrict__ bsum, int n) {
  int i = blockIdx.x * 256 + threadIdx.x;
  if (i < n) offs[i] += bsum[blockIdx.x];
}

// ---------------- CSR bucket fill: offs doubles as cursor ----------------
// Afterwards node n's slots are [ (n ? offs[n-1] : 0), offs[n] ).
__global__ __launch_bounds__(256) void fill_kernel(const int* __restrict__ src,
                                                   const int* __restrict__ dst,
                                                   int* __restrict__ offs,
                                                   int2* __restrict__ csr, int n_edges) {
  int i = blockIdx.x * blockDim.x + threadIdx.x;
  int stride = gridDim.x * blockDim.x;
  for (; i < n_edges; i += stride) {
    int d = __builtin_nontemporal_load(&dst[i]);
    int s = __builtin_nontemporal_load(&src[i]);
    int p = atomicAdd(&offs[d], 1);
    csr[p] = make_int2(i, s);
  }
}

// ---------------- hop 1: 16 lanes x float4 per row, 4 rows per wave-load ----------------
__global__ __launch_bounds__(256) void h1_kernel(const float* __restrict__ edge_feat,
                                                 const int2* __restrict__ csr,
                                                 const int* __restrict__ offs,
                                                 float* __restrict__ h1, int n_nodes) {
  int n = blockIdx.x * 4 + (threadIdx.x >> 6);
  if (n >= n_nodes) return;
  int l = threadIdx.x & 63;
  int l15 = l & 15, l4 = l >> 4;
  int kb = n ? offs[n - 1] : 0;
  int ke = offs[n];
  f32x4 acc0 = {0.f, 0.f, 0.f, 0.f}, acc1 = {0.f, 0.f, 0.f, 0.f};
  int k = kb;
  for (; k + 8 <= ke; k += 8) {
    int e0 = csr[k + l4].x;
    int e1 = csr[k + 4 + l4].x;
    f32x4 v0 = __builtin_nontemporal_load((const f32x4*)&edge_feat[(size_t)e0 * NF + l15 * 4]);
    f32x4 v1 = __builtin_nontemporal_load((const f32x4*)&edge_feat[(size_t)e1 * NF + l15 * 4]);
    acc0 += v0;
    acc1 += v1;
  }
  if (k + 4 <= ke) {
    int e = csr[k + l4].x;
    acc0 += __builtin_nontemporal_load((const f32x4*)&edge_feat[(size_t)e * NF + l15 * 4]);
    k += 4;
  }
  int rem = ke - k;   // 0..3
  if (l4 < rem) {
    int e = csr[k + l4].x;
    acc1 += __builtin_nontemporal_load((const f32x4*)&edge_feat[(size_t)e * NF + l15 * 4]);
  }
  f32x4 t = acc0 + acc1;
  t += sx4(t, 16);
  t += sx4(t, 32);
  if (l4 == 0) *(f32x4*)&h1[(size_t)n * NF + l15 * 4] = t;
}

// ---------------- hop 2: same structure, rows from h1 (cached) ----------------
__global__ __launch_bounds__(256) void h2_kernel(const float* __restrict__ h1,
                                                 const int2* __restrict__ csr,
                                                 const int* __restrict__ offs,
                                                 float* __restrict__ h2, int n_nodes) {
  int n = blockIdx.x * 4 + (threadIdx.x >> 6);
  if (n >= n_nodes) return;
  int l = threadIdx.x & 63;
  int l15 = l & 15, l4 = l >> 4;
  int kb = n ? offs[n - 1] : 0;
  int ke = offs[n];
  f32x4 acc0 = {0.f, 0.f, 0.f, 0.f}, acc1 = {0.f, 0.f, 0.f, 0.f};
  int k = kb;
  for (; k + 8 <= ke; k += 8) {
    int s0 = csr[k + l4].y;
    int s1 = csr[k + 4 + l4].y;
    acc0 += *(const f32x4*)&h1[(size_t)s0 * NF + l15 * 4];
    acc1 += *(const f32x4*)&h1[(size_t)s1 * NF + l15 * 4];
  }
  if (k + 4 <= ke) {
    int s = csr[k + l4].y;
    acc0 += *(const f32x4*)&h1[(size_t)s * NF + l15 * 4];
    k += 4;
  }
  int rem = ke - k;
  if (l4 < rem) {
    int s = csr[k + l4].y;
    acc1 += *(const f32x4*)&h1[(size_t)s * NF + l15 * 4];
  }
  f32x4 t = acc0 + acc1;
  t += sx4(t, 16);
  t += sx4(t, 32);
  if (l4 == 0) *(f32x4*)&h2[(size_t)n * NF + l15 * 4] = t;
}

// ---------------- GEMM via bf16 MFMA; writes rst (f32, NT) + rstb (bf16 shadow) ----
__global__ __launch_bounds__(256) void gemm_kernel(const float* __restrict__ node_feat,
                                                   const float* __restrict__ h1,
                                                   const float* __restrict__ h2,
                                                   const float* __restrict__ norm,
                                                   const float* __restrict__ W,
                                                   const float* __restrict__ bias,
                                                   float* __restrict__ rst,
                                                   short* __restrict__ rstb, int n_nodes) {
  __shared__ short F[32 * 200];   // bf16 A-tile
  __shared__ float R[32][132];    // f32 result tile (+4 pad)
  int tid = threadIdx.x;
  int l = tid & 63, w = tid >> 6;
  int l15 = l & 15, l4 = l >> 4;

  bf16x8 Bf[6][2];
  #pragma unroll
  for (int c = 0; c < 2; ++c) {
    int col = w * 32 + c * 16 + l15;
    const float* wp = &W[(size_t)col * CAT];
    #pragma unroll
    for (int ks = 0; ks < 6; ++ks) {
      int k0 = ks * 32 + l4 * 8;
      bf16x8 b;
      #pragma unroll
      for (int j = 0; j < 8; ++j) b[j] = f2bf(wp[k0 + j]);
      Bf[ks][c] = b;
    }
  }
  float bias0 = bias[w * 32 + l15];
  float bias1 = bias[w * 32 + 16 + l15];

  int tiles = (n_nodes + 31) / 32;
  for (int tile = blockIdx.x; tile < tiles; tile += gridDim.x) {
    int nbase = tile * 32;
    __syncthreads();   // previous iteration's readers done with F and R
    for (int idx = tid; idx < 768; idx += 256) {
      int m = idx / 24, q = idx - m * 24;
      int n = nbase + m;
      bf16x8 pk;
      if (n < n_nodes) {
        const float* sp;
        float scale = 1.f;
        if (q < 8)       sp = &node_feat[(size_t)n * NF + q * 8];
        else if (q < 16) { sp = &h1[(size_t)n * NF + (q - 8) * 8]; scale = norm[n]; }
        else             { sp = &h2[(size_t)n * NF + (q - 16) * 8]; scale = norm[n]; }
        f32x4 v0 = *(const f32x4*)sp;
        f32x4 v1 = *(const f32x4*)(sp + 4);
        pk[0] = f2bf(v0.x * scale); pk[1] = f2bf(v0.y * scale);
        pk[2] = f2bf(v0.z * scale); pk[3] = f2bf(v0.w * scale);
        pk[4] = f2bf(v1.x * scale); pk[5] = f2bf(v1.y * scale);
        pk[6] = f2bf(v1.z * scale); pk[7] = f2bf(v1.w * scale);
      } else {
        pk = bf16x8{0,0,0,0,0,0,0,0};
      }
      *(bf16x8*)&F[m * 200 + q * 8] = pk;
    }
    __syncthreads();
    f32x4 acc00 = {0.f,0.f,0.f,0.f}, acc01 = {0.f,0.f,0.f,0.f};
    f32x4 acc10 = {0.f,0.f,0.f,0.f}, acc11 = {0.f,0.f,0.f,0.f};
    #pragma unroll
    for (int ks = 0; ks < 6; ++ks) {
      bf16x8 a0 = *(const bf16x8*)&F[l15 * 200 + ks * 32 + l4 * 8];
      bf16x8 a1 = *(const bf16x8*)&F[(16 + l15) * 200 + ks * 32 + l4 * 8];
      acc00 = __builtin_amdgcn_mfma_f32_16x16x32_bf16(a0, Bf[ks][0], acc00, 0, 0, 0);
      acc01 = __builtin_amdgcn_mfma_f32_16x16x32_bf16(a0, Bf[ks][1], acc01, 0, 0, 0);
      acc10 = __builtin_amdgcn_mfma_f32_16x16x32_bf16(a1, Bf[ks][0], acc10, 0, 0, 0);
      acc11 = __builtin_amdgcn_mfma_f32_16x16x32_bf16(a1, Bf[ks][1], acc11, 0, 0, 0);
    }
    // stage tile: D[row=rt*16+l4*4+r][col=w*32+(c16)+l15]
    #pragma unroll
    for (int rt = 0; rt < 2; ++rt) {
      f32x4 ac0 = rt ? acc10 : acc00;
      f32x4 ac1 = rt ? acc11 : acc01;
      #pragma unroll
      for (int r = 0; r < 4; ++r) {
        int row = rt * 16 + l4 * 4 + r;
        R[row][w * 32 + l15] = ac0[r] + bias0;
        R[row][w * 32 + 16 + l15] = ac1[r] + bias1;
      }
    }
    __syncthreads();
    // rst write: coalesced f32x4, NT (never re-read)
    for (int idx = tid; idx < 32 * 32; idx += 256) {
      int m = idx >> 5, c = idx & 31;
      int n = nbase + m;
      if (n < n_nodes) {
        f32x4 v = *(const f32x4*)&R[m][c * 4];
        __builtin_nontemporal_store(v, (f32x4*)&rst[(size_t)n * N_OUT + c * 4]);
      }
    }
    // bf16 shadow write (re-read by est: keep cacheable)
    if (rstb) {
      for (int idx = tid; idx < 32 * 16; idx += 256) {
        int m = idx >> 4, q = idx & 15;
        int n = nbase + m;
        if (n < n_nodes) {
          const float* rp = &R[m][q * 8];
          bf16x8 pk;
          #pragma unroll
          for (int j = 0; j < 8; ++j) pk[j] = f2bf(rp[j]);
          *(bf16x8*)&rstb[(size_t)n * N_OUT + q * 8] = pk;
        }
      }
    }
  }
}

// ---------------- est from bf16 shadow: sequential NT write, 256B gathers ----------
__global__ __launch_bounds__(256) void est_bf16_kernel(const short* __restrict__ rstb,
                                                       const int* __restrict__ src,
                                                       float* __restrict__ est, int n_edges) {
  f32x4* e4 = (f32x4*)est;
  int total = n_edges * 32;
  int i = blockIdx.x * blockDim.x + threadIdx.x;
  int stride = gridDim.x * blockDim.x;
  for (; i < total; i += stride) {
    int e = i >> 5, c = i & 31;
    ushort4 b = *(const ushort4*)&rstb[(size_t)src[e] * N_OUT + c * 4];
    f32x4 v;
    v.x = __uint_as_float((unsigned)b.x << 16);
    v.y = __uint_as_float((unsigned)b.y << 16);
    v.z = __uint_as_float((unsigned)b.z << 16);
    v.w = __uint_as_float((unsigned)b.w << 16);
    __builtin_nontemporal_store(v, &e4[i]);
  }
}

// ---------------- fallback est (f32 read) if ws can't fit rstb ----------------
__global__ __launch_bounds__(256) void est_f32_kernel(const float* __restrict__ rst,
                                                      const int* __restrict__ src,
                                                      float* __restrict__ est, int n_edges) {
  const f32x4* r4 = (const f32x4*)rst;
  f32x4* e4 = (f32x4*)est;
  int total = n_edges * 32;
  int i = blockIdx.x * blockDim.x + threadIdx.x;
  int stride = gridDim.x * blockDim.x;
  for (; i < total; i += stride) {
    int e = i >> 5, c = i & 31;
    f32x4 v = r4[(size_t)src[e] * 32 + c];
    __builtin_nontemporal_store(v, &e4[i]);
  }
}

extern "C" void kernel_launch(void* const* d_in, const int* in_sizes, int n_in,
                              void* d_out, int out_size, void* d_ws, size_t ws_size,
                              hipStream_t stream) {
  const float* node_feat = (const float*)d_in[0];
  const float* edge_feat = (const float*)d_in[1];
  const float* W = (const float*)d_in[2];
  const float* bias = (const float*)d_in[3];
  const int* src = (const int*)d_in[4];
  const int* dst = (const int*)d_in[5];
  int n_nodes = in_sizes[0] / NF;
  int n_edges = in_sizes[4];

  size_t off = 0;
  auto take = [&](size_t bytes) -> void* {
    void* p = (char*)d_ws + off;
    off += (bytes + 255) & ~(size_t)255;
    return p;
  };
  int* deg = (int*)take((size_t)n_nodes * 4);
  int* offs = (int*)take(((size_t)n_nodes + 1) * 4);
  float* norm = (float*)take((size_t)n_nodes * 4);
  int* bsum = (int*)take(256 * 4);
  int2* csr = (int2*)take((size_t)n_edges * 8);
  float* h1 = (float*)take((size_t)n_nodes * NF * 4);
  float* h2 = (float*)take((size_t)n_nodes * NF * 4);
  // bf16 shadow of rst, if it fits in the workspace
  size_t rstb_bytes = (size_t)n_nodes * N_OUT * 2;
  short* rstb = nullptr;
  if (off + rstb_bytes <= ws_size) rstb = (short*)take(rstb_bytes);

  float* rst = (float*)d_out;
  float* est = rst + (size_t)n_nodes * N_OUT;

  hipMemsetAsync(deg, 0, (size_t)n_nodes * 4, stream);

  deg_kernel<<<2048, 256, 0, stream>>>(dst, deg, n_edges);
  int nbs = (n_nodes + 255) / 256;
  scanA_kernel<<<nbs, 256, 0, stream>>>(deg, offs, norm, bsum, n_nodes);
  scanB_kernel<<<1, 256, 0, stream>>>(bsum, nbs);
  scanC_kernel<<<nbs, 256, 0, stream>>>(offs, bsum, n_nodes);
  fill_kernel<<<2048, 256, 0, stream>>>(src, dst, offs, csr, n_edges);
  int nb = (n_nodes + 3) / 4;
  h1_kernel<<<nb, 256, 0, stream>>>(edge_feat, csr, offs, h1, n_nodes);
  h2_kernel<<<nb, 256, 0, stream>>>(h1, csr, offs, h2, n_nodes);
  gemm_kernel<<<320, 256, 0, stream>>>(node_feat, h1, h2, norm, W, bias,
                                       rst, rstb, n_nodes);
  if (rstb)
    est_bf16_kernel<<<4096, 256, 0, stream>>>(rstb, src, est, n_edges);
  else
    est_f32_kernel<<<4096, 256, 0, stream>>>(rst, src, est, n_edges);
}

// Round 9
// 382.798 us; speedup vs baseline: 2.6201x; 1.0168x over previous
//
#include <hip/hip_runtime.h>
#include <hip/hip_bf16.h>

#define NF 64        // node/edge feature dim
#define N_OUT 128    // output dim
#define CAT 192      // concat dim = 3*64

typedef __attribute__((ext_vector_type(4))) float f32x4;
typedef __attribute__((ext_vector_type(8))) short bf16x8;

__device__ inline short f2bf(float x) {   // round-to-nearest-even bf16
  unsigned u = __float_as_uint(x);
  unsigned r = (u + 0x7fff + ((u >> 16) & 1)) >> 16;
  return (short)r;
}

__device__ inline f32x4 sx4(f32x4 v, int m) {
  f32x4 r;
  r.x = __shfl_xor(v.x, m, 64);
  r.y = __shfl_xor(v.y, m, 64);
  r.z = __shfl_xor(v.z, m, 64);
  r.w = __shfl_xor(v.w, m, 64);
  return r;
}

// ---------------- degree histogram ----------------
__global__ __launch_bounds__(256) void deg_kernel(const int* __restrict__ dst,
                                                  int* __restrict__ deg, int n_edges) {
  int i = blockIdx.x * blockDim.x + threadIdx.x;
  int stride = gridDim.x * blockDim.x;
  for (; i < n_edges; i += stride) {
    int d = __builtin_nontemporal_load(&dst[i]);
    atomicAdd(&deg[d], 1);
  }
}

// ---------------- scan pass A: per-block exclusive scan + block sums ----------------
__global__ __launch_bounds__(256) void scanA_kernel(const int* __restrict__ deg,
                                                    int* __restrict__ offs,
                                                    float* __restrict__ norm,
                                                    int* __restrict__ bsum, int n) {
  int tid = threadIdx.x;
  int i = blockIdx.x * 256 + tid;
  int lane = tid & 63, wid = tid >> 6;
  int v = (i < n) ? deg[i] : 0;
  int s = v;
  #pragma unroll
  for (int o = 1; o < 64; o <<= 1) {
    int t = __shfl_up(s, o, 64);
    if (lane >= o) s += t;
  }
  __shared__ int ws[4], wb[4];
  if (lane == 63) ws[wid] = s;
  __syncthreads();
  if (tid == 0) {
    int run = 0;
    #pragma unroll
    for (int w = 0; w < 4; ++w) { wb[w] = run; run += ws[w]; }
    bsum[blockIdx.x] = run;
  }
  __syncthreads();
  if (i < n) {
    offs[i] = wb[wid] + s - v;
    norm[i] = rsqrtf(fmaxf((float)v, 1.0f));
  }
}

// ---------------- scan pass BC (merged): every block scans all block sums, adds own base ----
__global__ __launch_bounds__(256) void scanBC_kernel(const int* __restrict__ bsum,
                                                     int* __restrict__ offs, int n, int nb) {
  int tid = threadIdx.x, lane = tid & 63, wid = tid >> 6;
  int v = (tid < nb) ? bsum[tid] : 0;
  int s = v;
  #pragma unroll
  for (int o = 1; o < 64; o <<= 1) {
    int t = __shfl_up(s, o, 64);
    if (lane >= o) s += t;
  }
  __shared__ int ws[4], wb[4];
  if (lane == 63) ws[wid] = s;
  __syncthreads();
  if (tid == 0) {
    int run = 0;
    #pragma unroll
    for (int w = 0; w < 4; ++w) { wb[w] = run; run += ws[w]; }
  }
  __syncthreads();
  __shared__ int sbase;
  if (tid == blockIdx.x) sbase = wb[wid] + s - v;   // exclusive scanned bsum[blockIdx.x]
  __syncthreads();
  int i = blockIdx.x * 256 + tid;
  if (i < n) offs[i] += sbase;
}

// ---------------- CSR bucket fill: offs doubles as cursor ----------------
// Afterwards node n's slots are [ (n ? offs[n-1] : 0), offs[n] ).
__global__ __launch_bounds__(256) void fill_kernel(const int* __restrict__ src,
                                                   const int* __restrict__ dst,
                                                   int* __restrict__ offs,
                                                   long long* __restrict__ csr, int n_edges) {
  int i = blockIdx.x * blockDim.x + threadIdx.x;
  int stride = gridDim.x * blockDim.x;
  for (; i < n_edges; i += stride) {
    int d = __builtin_nontemporal_load(&dst[i]);
    int s = __builtin_nontemporal_load(&src[i]);
    int p = atomicAdd(&offs[d], 1);
    // pack: low word = edge id (int2.x), high word = src (int2.y)
    long long pk = (long long)(((unsigned long long)(unsigned)s << 32) | (unsigned)i);
    __builtin_nontemporal_store(pk, &csr[p]);
  }
}

// ---------------- hop 1: 16 lanes x float4 per row, 16 edges/iter ----------------
__global__ __launch_bounds__(256) void h1_kernel(const float* __restrict__ edge_feat,
                                                 const int2* __restrict__ csr,
                                                 const int* __restrict__ offs,
                                                 float* __restrict__ h1, int n_nodes) {
  int n = blockIdx.x * 4 + (threadIdx.x >> 6);
  if (n >= n_nodes) return;
  int l = threadIdx.x & 63;
  int l15 = l & 15, l4 = l >> 4;
  int kb = n ? offs[n - 1] : 0;
  int ke = offs[n];
  f32x4 acc0 = {0.f,0.f,0.f,0.f}, acc1 = {0.f,0.f,0.f,0.f};
  f32x4 acc2 = {0.f,0.f,0.f,0.f}, acc3 = {0.f,0.f,0.f,0.f};
  int k = kb;
  for (; k + 16 <= ke; k += 16) {
    int e0 = csr[k + l4].x;
    int e1 = csr[k + 4 + l4].x;
    int e2 = csr[k + 8 + l4].x;
    int e3 = csr[k + 12 + l4].x;
    acc0 += __builtin_nontemporal_load((const f32x4*)&edge_feat[(size_t)e0 * NF + l15 * 4]);
    acc1 += __builtin_nontemporal_load((const f32x4*)&edge_feat[(size_t)e1 * NF + l15 * 4]);
    acc2 += __builtin_nontemporal_load((const f32x4*)&edge_feat[(size_t)e2 * NF + l15 * 4]);
    acc3 += __builtin_nontemporal_load((const f32x4*)&edge_feat[(size_t)e3 * NF + l15 * 4]);
  }
  if (k + 8 <= ke) {
    int e0 = csr[k + l4].x;
    int e1 = csr[k + 4 + l4].x;
    acc0 += __builtin_nontemporal_load((const f32x4*)&edge_feat[(size_t)e0 * NF + l15 * 4]);
    acc1 += __builtin_nontemporal_load((const f32x4*)&edge_feat[(size_t)e1 * NF + l15 * 4]);
    k += 8;
  }
  if (k + 4 <= ke) {
    int e = csr[k + l4].x;
    acc2 += __builtin_nontemporal_load((const f32x4*)&edge_feat[(size_t)e * NF + l15 * 4]);
    k += 4;
  }
  int rem = ke - k;   // 0..3
  if (l4 < rem) {
    int e = csr[k + l4].x;
    acc3 += __builtin_nontemporal_load((const f32x4*)&edge_feat[(size_t)e * NF + l15 * 4]);
  }
  f32x4 t = (acc0 + acc1) + (acc2 + acc3);
  t += sx4(t, 16);
  t += sx4(t, 32);
  if (l4 == 0) *(f32x4*)&h1[(size_t)n * NF + l15 * 4] = t;
}

// ---------------- hop 2: same structure, rows from h1 (cached) ----------------
__global__ __launch_bounds__(256) void h2_kernel(const float* __restrict__ h1,
                                                 const int2* __restrict__ csr,
                                                 const int* __restrict__ offs,
                                                 float* __restrict__ h2, int n_nodes) {
  int n = blockIdx.x * 4 + (threadIdx.x >> 6);
  if (n >= n_nodes) return;
  int l = threadIdx.x & 63;
  int l15 = l & 15, l4 = l >> 4;
  int kb = n ? offs[n - 1] : 0;
  int ke = offs[n];
  f32x4 acc0 = {0.f,0.f,0.f,0.f}, acc1 = {0.f,0.f,0.f,0.f};
  f32x4 acc2 = {0.f,0.f,0.f,0.f}, acc3 = {0.f,0.f,0.f,0.f};
  int k = kb;
  for (; k + 16 <= ke; k += 16) {
    int s0 = csr[k + l4].y;
    int s1 = csr[k + 4 + l4].y;
    int s2 = csr[k + 8 + l4].y;
    int s3 = csr[k + 12 + l4].y;
    acc0 += *(const f32x4*)&h1[(size_t)s0 * NF + l15 * 4];
    acc1 += *(const f32x4*)&h1[(size_t)s1 * NF + l15 * 4];
    acc2 += *(const f32x4*)&h1[(size_t)s2 * NF + l15 * 4];
    acc3 += *(const f32x4*)&h1[(size_t)s3 * NF + l15 * 4];
  }
  if (k + 8 <= ke) {
    int s0 = csr[k + l4].y;
    int s1 = csr[k + 4 + l4].y;
    acc0 += *(const f32x4*)&h1[(size_t)s0 * NF + l15 * 4];
    acc1 += *(const f32x4*)&h1[(size_t)s1 * NF + l15 * 4];
    k += 8;
  }
  if (k + 4 <= ke) {
    int s = csr[k + l4].y;
    acc2 += *(const f32x4*)&h1[(size_t)s * NF + l15 * 4];
    k += 4;
  }
  int rem = ke - k;
  if (l4 < rem) {
    int s = csr[k + l4].y;
    acc3 += *(const f32x4*)&h1[(size_t)s * NF + l15 * 4];
  }
  f32x4 t = (acc0 + acc1) + (acc2 + acc3);
  t += sx4(t, 16);
  t += sx4(t, 32);
  if (l4 == 0) *(f32x4*)&h2[(size_t)n * NF + l15 * 4] = t;
}

// ---------------- GEMM via bf16 MFMA: 512 thr, 64-node tile, rst + bf16 shadow ----
// 8 waves: w2 = w&3 -> output cols [w2*32, w2*32+32); wh = w>>2 -> node rows
// [wh*32, wh*32+32). 2 blocks/CU (59 KB LDS), 16 waves/CU.
__global__ __launch_bounds__(512) void gemm_kernel(const float* __restrict__ node_feat,
                                                   const float* __restrict__ h1,
                                                   const float* __restrict__ h2,
                                                   const float* __restrict__ norm,
                                                   const float* __restrict__ W,
                                                   const float* __restrict__ bias,
                                                   float* __restrict__ rst,
                                                   short* __restrict__ rstb, int n_nodes) {
  __shared__ short F[64 * 200];   // bf16 A-tile, 25600 B
  __shared__ float R[64][132];    // f32 result tile (+4 pad), 33792 B
  int tid = threadIdx.x;
  int l = tid & 63, w = tid >> 6;
  int w2 = w & 3, wh = w >> 2;
  int l15 = l & 15, l4 = l >> 4;

  bf16x8 Bf[6][2];
  #pragma unroll
  for (int c = 0; c < 2; ++c) {
    int col = w2 * 32 + c * 16 + l15;
    const float* wp = &W[(size_t)col * CAT];
    #pragma unroll
    for (int ks = 0; ks < 6; ++ks) {
      int k0 = ks * 32 + l4 * 8;
      bf16x8 b;
      #pragma unroll
      for (int j = 0; j < 8; ++j) b[j] = f2bf(wp[k0 + j]);
      Bf[ks][c] = b;
    }
  }
  float bias0 = bias[w2 * 32 + l15];
  float bias1 = bias[w2 * 32 + 16 + l15];

  int tiles = (n_nodes + 63) / 64;
  for (int tile = blockIdx.x; tile < tiles; tile += gridDim.x) {
    int nbase = tile * 64;
    __syncthreads();   // previous iteration's readers done with F and R
    for (int idx = tid; idx < 1536; idx += 512) {
      int m = idx / 24, q = idx - m * 24;
      int n = nbase + m;
      bf16x8 pk;
      if (n < n_nodes) {
        const float* sp;
        float scale = 1.f;
        if (q < 8)       sp = &node_feat[(size_t)n * NF + q * 8];
        else if (q < 16) { sp = &h1[(size_t)n * NF + (q - 8) * 8]; scale = norm[n]; }
        else             { sp = &h2[(size_t)n * NF + (q - 16) * 8]; scale = norm[n]; }
        f32x4 v0 = *(const f32x4*)sp;
        f32x4 v1 = *(const f32x4*)(sp + 4);
        pk[0] = f2bf(v0.x * scale); pk[1] = f2bf(v0.y * scale);
        pk[2] = f2bf(v0.z * scale); pk[3] = f2bf(v0.w * scale);
        pk[4] = f2bf(v1.x * scale); pk[5] = f2bf(v1.y * scale);
        pk[6] = f2bf(v1.z * scale); pk[7] = f2bf(v1.w * scale);
      } else {
        pk = bf16x8{0,0,0,0,0,0,0,0};
      }
      *(bf16x8*)&F[m * 200 + q * 8] = pk;
    }
    __syncthreads();
    f32x4 acc00 = {0.f,0.f,0.f,0.f}, acc01 = {0.f,0.f,0.f,0.f};
    f32x4 acc10 = {0.f,0.f,0.f,0.f}, acc11 = {0.f,0.f,0.f,0.f};
    #pragma unroll
    for (int ks = 0; ks < 6; ++ks) {
      bf16x8 a0 = *(const bf16x8*)&F[(wh * 32 + l15) * 200 + ks * 32 + l4 * 8];
      bf16x8 a1 = *(const bf16x8*)&F[(wh * 32 + 16 + l15) * 200 + ks * 32 + l4 * 8];
      acc00 = __builtin_amdgcn_mfma_f32_16x16x32_bf16(a0, Bf[ks][0], acc00, 0, 0, 0);
      acc01 = __builtin_amdgcn_mfma_f32_16x16x32_bf16(a0, Bf[ks][1], acc01, 0, 0, 0);
      acc10 = __builtin_amdgcn_mfma_f32_16x16x32_bf16(a1, Bf[ks][0], acc10, 0, 0, 0);
      acc11 = __builtin_amdgcn_mfma_f32_16x16x32_bf16(a1, Bf[ks][1], acc11, 0, 0, 0);
    }
    // stage: D[row = wh*32 + rt*16 + l4*4 + r][col = w2*32 + (c?16:0) + l15]
    #pragma unroll
    for (int rt = 0; rt < 2; ++rt) {
      f32x4 ac0 = rt ? acc10 : acc00;
      f32x4 ac1 = rt ? acc11 : acc01;
      #pragma unroll
      for (int r = 0; r < 4; ++r) {
        int row = wh * 32 + rt * 16 + l4 * 4 + r;
        R[row][w2 * 32 + l15] = ac0[r] + bias0;
        R[row][w2 * 32 + 16 + l15] = ac1[r] + bias1;
      }
    }
    __syncthreads();
    // rst write: coalesced f32x4, NT (never re-read)
    for (int idx = tid; idx < 64 * 32; idx += 512) {
      int m = idx >> 5, c = idx & 31;
      int n = nbase + m;
      if (n < n_nodes) {
        f32x4 v = *(const f32x4*)&R[m][c * 4];
        __builtin_nontemporal_store(v, (f32x4*)&rst[(size_t)n * N_OUT + c * 4]);
      }
    }
    // bf16 shadow write (re-read by est: keep cacheable)
    if (rstb) {
      for (int idx = tid; idx < 64 * 16; idx += 512) {
        int m = idx >> 4, q = idx & 15;
        int n = nbase + m;
        if (n < n_nodes) {
          const float* rp = &R[m][q * 8];
          bf16x8 pk;
          #pragma unroll
          for (int j = 0; j < 8; ++j) pk[j] = f2bf(rp[j]);
          *(bf16x8*)&rstb[(size_t)n * N_OUT + q * 8] = pk;
        }
      }
    }
  }
}

// ---------------- est from bf16 shadow: sequential NT write, 256B gathers ----------
__global__ __launch_bounds__(256) void est_bf16_kernel(const short* __restrict__ rstb,
                                                       const int* __restrict__ src,
                                                       float* __restrict__ est, int n_edges) {
  f32x4* e4 = (f32x4*)est;
  int total = n_edges * 32;
  int i = blockIdx.x * blockDim.x + threadIdx.x;
  int stride = gridDim.x * blockDim.x;
  for (; i < total; i += stride) {
    int e = i >> 5, c = i & 31;
    ushort4 b = *(const ushort4*)&rstb[(size_t)src[e] * N_OUT + c * 4];
    f32x4 v;
    v.x = __uint_as_float((unsigned)b.x << 16);
    v.y = __uint_as_float((unsigned)b.y << 16);
    v.z = __uint_as_float((unsigned)b.z << 16);
    v.w = __uint_as_float((unsigned)b.w << 16);
    __builtin_nontemporal_store(v, &e4[i]);
  }
}

// ---------------- fallback est (f32 read) if ws can't fit rstb ----------------
__global__ __launch_bounds__(256) void est_f32_kernel(const float* __restrict__ rst,
                                                      const int* __restrict__ src,
                                                      float* __restrict__ est, int n_edges) {
  const f32x4* r4 = (const f32x4*)rst;
  f32x4* e4 = (f32x4*)est;
  int total = n_edges * 32;
  int i = blockIdx.x * blockDim.x + threadIdx.x;
  int stride = gridDim.x * blockDim.x;
  for (; i < total; i += stride) {
    int e = i >> 5, c = i & 31;
    f32x4 v = r4[(size_t)src[e] * 32 + c];
    __builtin_nontemporal_store(v, &e4[i]);
  }
}

extern "C" void kernel_launch(void* const* d_in, const int* in_sizes, int n_in,
                              void* d_out, int out_size, void* d_ws, size_t ws_size,
                              hipStream_t stream) {
  const float* node_feat = (const float*)d_in[0];
  const float* edge_feat = (const float*)d_in[1];
  const float* W = (const float*)d_in[2];
  const float* bias = (const float*)d_in[3];
  const int* src = (const int*)d_in[4];
  const int* dst = (const int*)d_in[5];
  int n_nodes = in_sizes[0] / NF;
  int n_edges = in_sizes[4];

  size_t off = 0;
  auto take = [&](size_t bytes) -> void* {
    void* p = (char*)d_ws + off;
    off += (bytes + 255) & ~(size_t)255;
    return p;
  };
  int* deg = (int*)take((size_t)n_nodes * 4);
  int* offs = (int*)take(((size_t)n_nodes + 1) * 4);
  float* norm = (float*)take((size_t)n_nodes * 4);
  int* bsum = (int*)take(256 * 4);
  long long* csr = (long long*)take((size_t)n_edges * 8);
  float* h1 = (float*)take((size_t)n_nodes * NF * 4);
  float* h2 = (float*)take((size_t)n_nodes * NF * 4);
  size_t rstb_bytes = (size_t)n_nodes * N_OUT * 2;
  short* rstb = nullptr;
  if (off + rstb_bytes <= ws_size) rstb = (short*)take(rstb_bytes);

  float* rst = (float*)d_out;
  float* est = rst + (size_t)n_nodes * N_OUT;

  (void)hipMemsetAsync(deg, 0, (size_t)n_nodes * 4, stream);

  deg_kernel<<<2048, 256, 0, stream>>>(dst, deg, n_edges);
  int nbs = (n_nodes + 255) / 256;
  scanA_kernel<<<nbs, 256, 0, stream>>>(deg, offs, norm, bsum, n_nodes);
  scanBC_kernel<<<nbs, 256, 0, stream>>>(bsum, offs, n_nodes, nbs);
  fill_kernel<<<2048, 256, 0, stream>>>(src, dst, offs, csr, n_edges);
  int nb = (n_nodes + 3) / 4;
  h1_kernel<<<nb, 256, 0, stream>>>(edge_feat, (const int2*)csr, offs, h1, n_nodes);
  h2_kernel<<<nb, 256, 0, stream>>>(h1, (const int2*)csr, offs, h2, n_nodes);
  gemm_kernel<<<512, 512, 0, stream>>>(node_feat, h1, h2, norm, W, bias,
                                       rst, rstb, n_nodes);
  if (rstb)
    est_bf16_kernel<<<8192, 256, 0, stream>>>(rstb, src, est, n_edges);
  else
    est_f32_kernel<<<8192, 256, 0, stream>>>(rst, src, est, n_edges);
}

// Round 10
// 381.125 us; speedup vs baseline: 2.6316x; 1.0044x over previous
//
#include <hip/hip_runtime.h>
#include <hip/hip_bf16.h>

#define NF 64        // node/edge feature dim
#define N_OUT 128    // output dim
#define CAT 192      // concat dim = 3*64

typedef __attribute__((ext_vector_type(4))) float f32x4;
typedef __attribute__((ext_vector_type(8))) short bf16x8;

__device__ inline unsigned short f2bf(float x) {   // round-to-nearest-even bf16
  unsigned u = __float_as_uint(x);
  unsigned r = (u + 0x7fff + ((u >> 16) & 1)) >> 16;
  return (unsigned short)r;
}

__device__ inline ushort4 pack4(f32x4 v) {
  ushort4 r;
  r.x = f2bf(v.x); r.y = f2bf(v.y); r.z = f2bf(v.z); r.w = f2bf(v.w);
  return r;
}

__device__ inline f32x4 unpack4(ushort4 b) {
  f32x4 v;
  v.x = __uint_as_float((unsigned)b.x << 16);
  v.y = __uint_as_float((unsigned)b.y << 16);
  v.z = __uint_as_float((unsigned)b.z << 16);
  v.w = __uint_as_float((unsigned)b.w << 16);
  return v;
}

__device__ inline f32x4 sx4(f32x4 v, int m) {
  f32x4 r;
  r.x = __shfl_xor(v.x, m, 64);
  r.y = __shfl_xor(v.y, m, 64);
  r.z = __shfl_xor(v.z, m, 64);
  r.w = __shfl_xor(v.w, m, 64);
  return r;
}

// ---------------- degree histogram ----------------
__global__ __launch_bounds__(256) void deg_kernel(const int* __restrict__ dst,
                                                  int* __restrict__ deg, int n_edges) {
  int i = blockIdx.x * blockDim.x + threadIdx.x;
  int stride = gridDim.x * blockDim.x;
  for (; i < n_edges; i += stride) {
    int d = __builtin_nontemporal_load(&dst[i]);
    atomicAdd(&deg[d], 1);
  }
}

// ---------------- scan pass A ----------------
__global__ __launch_bounds__(256) void scanA_kernel(const int* __restrict__ deg,
                                                    int* __restrict__ offs,
                                                    float* __restrict__ norm,
                                                    int* __restrict__ bsum, int n) {
  int tid = threadIdx.x;
  int i = blockIdx.x * 256 + tid;
  int lane = tid & 63, wid = tid >> 6;
  int v = (i < n) ? deg[i] : 0;
  int s = v;
  #pragma unroll
  for (int o = 1; o < 64; o <<= 1) {
    int t = __shfl_up(s, o, 64);
    if (lane >= o) s += t;
  }
  __shared__ int ws[4], wb[4];
  if (lane == 63) ws[wid] = s;
  __syncthreads();
  if (tid == 0) {
    int run = 0;
    #pragma unroll
    for (int w = 0; w < 4; ++w) { wb[w] = run; run += ws[w]; }
    bsum[blockIdx.x] = run;
  }
  __syncthreads();
  if (i < n) {
    offs[i] = wb[wid] + s - v;
    norm[i] = rsqrtf(fmaxf((float)v, 1.0f));
  }
}

// ---------------- scan pass BC ----------------
__global__ __launch_bounds__(256) void scanBC_kernel(const int* __restrict__ bsum,
                                                     int* __restrict__ offs, int n, int nb) {
  int tid = threadIdx.x, lane = tid & 63, wid = tid >> 6;
  int v = (tid < nb) ? bsum[tid] : 0;
  int s = v;
  #pragma unroll
  for (int o = 1; o < 64; o <<= 1) {
    int t = __shfl_up(s, o, 64);
    if (lane >= o) s += t;
  }
  __shared__ int ws[4], wb[4];
  if (lane == 63) ws[wid] = s;
  __syncthreads();
  if (tid == 0) {
    int run = 0;
    #pragma unroll
    for (int w = 0; w < 4; ++w) { wb[w] = run; run += ws[w]; }
  }
  __syncthreads();
  __shared__ int sbase;
  if (tid == blockIdx.x) sbase = wb[wid] + s - v;
  __syncthreads();
  int i = blockIdx.x * 256 + tid;
  if (i < n) offs[i] += sbase;
}

// ---------------- CSR bucket fill ----------------
__global__ __launch_bounds__(256) void fill_kernel(const int* __restrict__ src,
                                                   const int* __restrict__ dst,
                                                   int* __restrict__ offs,
                                                   long long* __restrict__ csr, int n_edges) {
  int i = blockIdx.x * blockDim.x + threadIdx.x;
  int stride = gridDim.x * blockDim.x;
  for (; i < n_edges; i += stride) {
    int d = __builtin_nontemporal_load(&dst[i]);
    int s = __builtin_nontemporal_load(&src[i]);
    int p = atomicAdd(&offs[d], 1);
    long long pk = (long long)(((unsigned long long)(unsigned)s << 32) | (unsigned)i);
    __builtin_nontemporal_store(pk, &csr[p]);
  }
}

// ---------------- hop 1: gather f32 edge rows -> h1r (bf16 raw) + h1n (bf16*norm);
//                  piggyback nfb = bf16(node_feat) ----------------
__global__ __launch_bounds__(256) void h1_kernel(const float* __restrict__ edge_feat,
                                                 const float* __restrict__ node_feat,
                                                 const int2* __restrict__ csr,
                                                 const int* __restrict__ offs,
                                                 const float* __restrict__ norm,
                                                 unsigned short* __restrict__ h1r,
                                                 unsigned short* __restrict__ h1n,
                                                 unsigned short* __restrict__ nfb,
                                                 int n_nodes) {
  int n = blockIdx.x * 4 + (threadIdx.x >> 6);
  if (n >= n_nodes) return;
  int l = threadIdx.x & 63;
  int l15 = l & 15, l4 = l >> 4;
  int kb = n ? offs[n - 1] : 0;
  int ke = offs[n];
  f32x4 acc0 = {0.f,0.f,0.f,0.f}, acc1 = {0.f,0.f,0.f,0.f};
  f32x4 acc2 = {0.f,0.f,0.f,0.f}, acc3 = {0.f,0.f,0.f,0.f};
  int k = kb;
  for (; k + 16 <= ke; k += 16) {
    int e0 = csr[k + l4].x;
    int e1 = csr[k + 4 + l4].x;
    int e2 = csr[k + 8 + l4].x;
    int e3 = csr[k + 12 + l4].x;
    acc0 += __builtin_nontemporal_load((const f32x4*)&edge_feat[(size_t)e0 * NF + l15 * 4]);
    acc1 += __builtin_nontemporal_load((const f32x4*)&edge_feat[(size_t)e1 * NF + l15 * 4]);
    acc2 += __builtin_nontemporal_load((const f32x4*)&edge_feat[(size_t)e2 * NF + l15 * 4]);
    acc3 += __builtin_nontemporal_load((const f32x4*)&edge_feat[(size_t)e3 * NF + l15 * 4]);
  }
  if (k + 8 <= ke) {
    int e0 = csr[k + l4].x;
    int e1 = csr[k + 4 + l4].x;
    acc0 += __builtin_nontemporal_load((const f32x4*)&edge_feat[(size_t)e0 * NF + l15 * 4]);
    acc1 += __builtin_nontemporal_load((const f32x4*)&edge_feat[(size_t)e1 * NF + l15 * 4]);
    k += 8;
  }
  if (k + 4 <= ke) {
    int e = csr[k + l4].x;
    acc2 += __builtin_nontemporal_load((const f32x4*)&edge_feat[(size_t)e * NF + l15 * 4]);
    k += 4;
  }
  int rem = ke - k;   // 0..3
  if (l4 < rem) {
    int e = csr[k + l4].x;
    acc3 += __builtin_nontemporal_load((const f32x4*)&edge_feat[(size_t)e * NF + l15 * 4]);
  }
  f32x4 t = (acc0 + acc1) + (acc2 + acc3);
  t += sx4(t, 16);
  t += sx4(t, 32);
  if (l4 == 0) {
    *(ushort4*)&h1r[(size_t)n * NF + l15 * 4] = pack4(t);
    float nm = norm[n];
    f32x4 tn = t; tn.x *= nm; tn.y *= nm; tn.z *= nm; tn.w *= nm;
    *(ushort4*)&h1n[(size_t)n * NF + l15 * 4] = pack4(tn);
  } else if (l4 == 1) {
    f32x4 v = *(const f32x4*)&node_feat[(size_t)n * NF + l15 * 4];
    *(ushort4*)&nfb[(size_t)n * NF + l15 * 4] = pack4(v);
  }
}

// ---------------- hop 2: gather bf16 h1r rows (L2-resident), write h2n = bf16(h2*norm) ----
__global__ __launch_bounds__(256) void h2_kernel(const unsigned short* __restrict__ h1r,
                                                 const int2* __restrict__ csr,
                                                 const int* __restrict__ offs,
                                                 const float* __restrict__ norm,
                                                 unsigned short* __restrict__ h2n,
                                                 int n_nodes) {
  int n = blockIdx.x * 4 + (threadIdx.x >> 6);
  if (n >= n_nodes) return;
  int l = threadIdx.x & 63;
  int l15 = l & 15, l4 = l >> 4;
  int kb = n ? offs[n - 1] : 0;
  int ke = offs[n];
  f32x4 acc0 = {0.f,0.f,0.f,0.f}, acc1 = {0.f,0.f,0.f,0.f};
  f32x4 acc2 = {0.f,0.f,0.f,0.f}, acc3 = {0.f,0.f,0.f,0.f};
  int k = kb;
  for (; k + 16 <= ke; k += 16) {
    int s0 = csr[k + l4].y;
    int s1 = csr[k + 4 + l4].y;
    int s2 = csr[k + 8 + l4].y;
    int s3 = csr[k + 12 + l4].y;
    acc0 += unpack4(*(const ushort4*)&h1r[(size_t)s0 * NF + l15 * 4]);
    acc1 += unpack4(*(const ushort4*)&h1r[(size_t)s1 * NF + l15 * 4]);
    acc2 += unpack4(*(const ushort4*)&h1r[(size_t)s2 * NF + l15 * 4]);
    acc3 += unpack4(*(const ushort4*)&h1r[(size_t)s3 * NF + l15 * 4]);
  }
  if (k + 8 <= ke) {
    int s0 = csr[k + l4].y;
    int s1 = csr[k + 4 + l4].y;
    acc0 += unpack4(*(const ushort4*)&h1r[(size_t)s0 * NF + l15 * 4]);
    acc1 += unpack4(*(const ushort4*)&h1r[(size_t)s1 * NF + l15 * 4]);
    k += 8;
  }
  if (k + 4 <= ke) {
    int s = csr[k + l4].y;
    acc2 += unpack4(*(const ushort4*)&h1r[(size_t)s * NF + l15 * 4]);
    k += 4;
  }
  int rem = ke - k;
  if (l4 < rem) {
    int s = csr[k + l4].y;
    acc3 += unpack4(*(const ushort4*)&h1r[(size_t)s * NF + l15 * 4]);
  }
  f32x4 t = (acc0 + acc1) + (acc2 + acc3);
  t += sx4(t, 16);
  t += sx4(t, 32);
  if (l4 == 0) {
    float nm = norm[n];
    t.x *= nm; t.y *= nm; t.z *= nm; t.w *= nm;
    *(ushort4*)&h2n[(size_t)n * NF + l15 * 4] = pack4(t);
  }
}

// ---------------- GEMM via bf16 MFMA: pure-copy staging from bf16 sources ----------
__global__ __launch_bounds__(512) void gemm_kernel(const unsigned short* __restrict__ nfb,
                                                   const unsigned short* __restrict__ h1n,
                                                   const unsigned short* __restrict__ h2n,
                                                   const float* __restrict__ W,
                                                   const float* __restrict__ bias,
                                                   float* __restrict__ rst,
                                                   unsigned short* __restrict__ rstb,
                                                   int n_nodes) {
  __shared__ short F[64 * 200];   // bf16 A-tile, 25600 B
  __shared__ float R[64][132];    // f32 result tile (+4 pad), 33792 B
  int tid = threadIdx.x;
  int l = tid & 63, w = tid >> 6;
  int w2 = w & 3, wh = w >> 2;
  int l15 = l & 15, l4 = l >> 4;

  bf16x8 Bf[6][2];
  #pragma unroll
  for (int c = 0; c < 2; ++c) {
    int col = w2 * 32 + c * 16 + l15;
    const float* wp = &W[(size_t)col * CAT];
    #pragma unroll
    for (int ks = 0; ks < 6; ++ks) {
      int k0 = ks * 32 + l4 * 8;
      bf16x8 b;
      #pragma unroll
      for (int j = 0; j < 8; ++j) b[j] = (short)f2bf(wp[k0 + j]);
      Bf[ks][c] = b;
    }
  }
  float bias0 = bias[w2 * 32 + l15];
  float bias1 = bias[w2 * 32 + 16 + l15];

  int tiles = (n_nodes + 63) / 64;
  for (int tile = blockIdx.x; tile < tiles; tile += gridDim.x) {
    int nbase = tile * 64;
    __syncthreads();   // previous iteration's readers done with F and R
    for (int idx = tid; idx < 1536; idx += 512) {
      int m = idx / 24, q = idx - m * 24;
      int n = nbase + m;
      bf16x8 pk = bf16x8{0,0,0,0,0,0,0,0};
      if (n < n_nodes) {
        const unsigned short* base = (q < 8) ? nfb : (q < 16) ? h1n : h2n;
        pk = *(const bf16x8*)&base[(size_t)n * NF + (q & 7) * 8];
      }
      *(bf16x8*)&F[m * 200 + q * 8] = pk;
    }
    __syncthreads();
    f32x4 acc00 = {0.f,0.f,0.f,0.f}, acc01 = {0.f,0.f,0.f,0.f};
    f32x4 acc10 = {0.f,0.f,0.f,0.f}, acc11 = {0.f,0.f,0.f,0.f};
    #pragma unroll
    for (int ks = 0; ks < 6; ++ks) {
      bf16x8 a0 = *(const bf16x8*)&F[(wh * 32 + l15) * 200 + ks * 32 + l4 * 8];
      bf16x8 a1 = *(const bf16x8*)&F[(wh * 32 + 16 + l15) * 200 + ks * 32 + l4 * 8];
      acc00 = __builtin_amdgcn_mfma_f32_16x16x32_bf16(a0, Bf[ks][0], acc00, 0, 0, 0);
      acc01 = __builtin_amdgcn_mfma_f32_16x16x32_bf16(a0, Bf[ks][1], acc01, 0, 0, 0);
      acc10 = __builtin_amdgcn_mfma_f32_16x16x32_bf16(a1, Bf[ks][0], acc10, 0, 0, 0);
      acc11 = __builtin_amdgcn_mfma_f32_16x16x32_bf16(a1, Bf[ks][1], acc11, 0, 0, 0);
    }
    #pragma unroll
    for (int rt = 0; rt < 2; ++rt) {
      f32x4 ac0 = rt ? acc10 : acc00;
      f32x4 ac1 = rt ? acc11 : acc01;
      #pragma unroll
      for (int r = 0; r < 4; ++r) {
        int row = wh * 32 + rt * 16 + l4 * 4 + r;
        R[row][w2 * 32 + l15] = ac0[r] + bias0;
        R[row][w2 * 32 + 16 + l15] = ac1[r] + bias1;
      }
    }
    __syncthreads();
    // rst write: coalesced f32x4, NT (never re-read)
    for (int idx = tid; idx < 64 * 32; idx += 512) {
      int m = idx >> 5, c = idx & 31;
      int n = nbase + m;
      if (n < n_nodes) {
        f32x4 v = *(const f32x4*)&R[m][c * 4];
        __builtin_nontemporal_store(v, (f32x4*)&rst[(size_t)n * N_OUT + c * 4]);
      }
    }
    // bf16 shadow write (re-read by est: keep cacheable)
    for (int idx = tid; idx < 64 * 16; idx += 512) {
      int m = idx >> 4, q = idx & 15;
      int n = nbase + m;
      if (n < n_nodes) {
        const float* rp = &R[m][q * 8];
        bf16x8 pk;
        #pragma unroll
        for (int j = 0; j < 8; ++j) pk[j] = (short)f2bf(rp[j]);
        *(bf16x8*)&rstb[(size_t)n * N_OUT + q * 8] = pk;
      }
    }
  }
}

// ---------------- est from bf16 shadow: sequential NT write, 256B gathers ----------
__global__ __launch_bounds__(256) void est_bf16_kernel(const unsigned short* __restrict__ rstb,
                                                       const int* __restrict__ src,
                                                       float* __restrict__ est, int n_edges) {
  f32x4* e4 = (f32x4*)est;
  int total = n_edges * 32;
  int i = blockIdx.x * blockDim.x + threadIdx.x;
  int stride = gridDim.x * blockDim.x;
  for (; i < total; i += stride) {
    int e = i >> 5, c = i & 31;
    ushort4 b = *(const ushort4*)&rstb[(size_t)src[e] * N_OUT + c * 4];
    __builtin_nontemporal_store(unpack4(b), &e4[i]);
  }
}

extern "C" void kernel_launch(void* const* d_in, const int* in_sizes, int n_in,
                              void* d_out, int out_size, void* d_ws, size_t ws_size,
                              hipStream_t stream) {
  const float* node_feat = (const float*)d_in[0];
  const float* edge_feat = (const float*)d_in[1];
  const float* W = (const float*)d_in[2];
  const float* bias = (const float*)d_in[3];
  const int* src = (const int*)d_in[4];
  const int* dst = (const int*)d_in[5];
  int n_nodes = in_sizes[0] / NF;
  int n_edges = in_sizes[4];

  size_t off = 0;
  auto take = [&](size_t bytes) -> void* {
    void* p = (char*)d_ws + off;
    off += (bytes + 255) & ~(size_t)255;
    return p;
  };
  int* deg = (int*)take((size_t)n_nodes * 4);
  int* offs = (int*)take(((size_t)n_nodes + 1) * 4);
  float* norm = (float*)take((size_t)n_nodes * 4);
  int* bsum = (int*)take(256 * 4);
  long long* csr = (long long*)take((size_t)n_edges * 8);
  unsigned short* h1r = (unsigned short*)take((size_t)n_nodes * NF * 2);
  unsigned short* h1n = (unsigned short*)take((size_t)n_nodes * NF * 2);
  unsigned short* h2n = (unsigned short*)take((size_t)n_nodes * NF * 2);
  unsigned short* nfb = (unsigned short*)take((size_t)n_nodes * NF * 2);
  unsigned short* rstb = (unsigned short*)take((size_t)n_nodes * N_OUT * 2);

  float* rst = (float*)d_out;
  float* est = rst + (size_t)n_nodes * N_OUT;

  (void)hipMemsetAsync(deg, 0, (size_t)n_nodes * 4, stream);

  deg_kernel<<<2048, 256, 0, stream>>>(dst, deg, n_edges);
  int nbs = (n_nodes + 255) / 256;
  scanA_kernel<<<nbs, 256, 0, stream>>>(deg, offs, norm, bsum, n_nodes);
  scanBC_kernel<<<nbs, 256, 0, stream>>>(bsum, offs, n_nodes, nbs);
  fill_kernel<<<2048, 256, 0, stream>>>(src, dst, offs, csr, n_edges);
  int nb = (n_nodes + 3) / 4;
  h1_kernel<<<nb, 256, 0, stream>>>(edge_feat, node_feat, (const int2*)csr, offs,
                                    norm, h1r, h1n, nfb, n_nodes);
  h2_kernel<<<nb, 256, 0, stream>>>(h1r, (const int2*)csr, offs, norm, h2n, n_nodes);
  gemm_kernel<<<512, 512, 0, stream>>>(nfb, h1n, h2n, W, bias, rst, rstb, n_nodes);
  est_bf16_kernel<<<8192, 256, 0, stream>>>(rstb, src, est, n_edges);
}